// Round 4
// baseline (160.290 us; speedup 1.0000x reference)
//
#include <hip/hip_runtime.h>

#define NSTEP 64
#define HDIM 1024
#define BDIM 2048
#define OHH 511

typedef float v2f __attribute__((ext_vector_type(2)));

// ---------------------------------------------------------------------------
// Packed FP32 (VOP3P) primitives. Coefficient pairs (c,sn) / (sp,cp) live in
// aligned VGPR pairs straight out of the dwordx4 load; op_sel/op_sel_hi give
// free per-half splats, neg_lo/neg_hi give free negation, and the swapped
// read in pk_fma_rot gives the i*t swizzle. 6 VOP3P ops per pair rotation,
// zero splat movs. (Compiler emits scalar v_fma_f32 otherwise — measured
// 47% VALUBusy ~= scalar instruction count across R0/R3.)
// ---------------------------------------------------------------------------
// d = ab.lo * x            (both halves multiplied by ab's low word)
__device__ __forceinline__ v2f pk_mul_lo(v2f ab, v2f x) {
    v2f d;
    asm("v_pk_mul_f32 %0, %1, %2 op_sel:[0,0] op_sel_hi:[0,1]"
        : "=v"(d) : "v"(ab), "v"(x));
    return d;
}
// d = -ab.hi * x + acc
__device__ __forceinline__ v2f pk_fnma_hi(v2f ab, v2f x, v2f acc) {
    v2f d;
    asm("v_pk_fma_f32 %0, %1, %2, %3 op_sel:[1,0,0] op_sel_hi:[1,1,1] neg_lo:[1,0,0] neg_hi:[1,0,0]"
        : "=v"(d) : "v"(ab), "v"(x), "v"(acc));
    return d;
}
// d = ab.hi * x + acc
__device__ __forceinline__ v2f pk_fma_hi(v2f ab, v2f x, v2f acc) {
    v2f d;
    asm("v_pk_fma_f32 %0, %1, %2, %3 op_sel:[1,0,0] op_sel_hi:[1,1,1]"
        : "=v"(d) : "v"(ab), "v"(x), "v"(acc));
    return d;
}
// d.lo = -pc.hi*t.hi + m.lo ; d.hi = pc.hi*t.lo + m.hi   (A' = (sp+i*cp)*t, cp part)
__device__ __forceinline__ v2f pk_fma_rot(v2f pc, v2f t, v2f m) {
    v2f d;
    asm("v_pk_fma_f32 %0, %1, %2, %3 op_sel:[1,1,0] op_sel_hi:[1,0,1] neg_lo:[1,0,0]"
        : "=v"(d) : "v"(pc), "v"(t), "v"(m));
    return d;
}

union f4p { float4 f; v2f h[2]; };   // h[0]=(c,sn), h[1]=(sp,cp)

// Full pair rotation on one (A,B) complex pair:
//   t = c*A - sn*B;  B' = c*B + sn*A;  A' = (sp + i*cp) * t
__device__ __forceinline__ void pair_rotp(const float4 f, v2f& A, v2f& B) {
    f4p u; u.f = f;
    v2f t  = pk_mul_lo(u.h[0], A);
    t      = pk_fnma_hi(u.h[0], B, t);
    v2f b2 = pk_mul_lo(u.h[0], B);
    B      = pk_fma_hi(u.h[0], A, b2);    // uses original A
    v2f m  = pk_mul_lo(u.h[1], t);
    A      = pk_fma_rot(u.h[1], t, m);
}
// Right-boundary variant: update A only, Bn is neighbor's value.
__device__ __forceinline__ void pair_rotp_a(const float4 f, v2f& A, const v2f Bn) {
    f4p u; u.f = f;
    v2f t = pk_mul_lo(u.h[0], A);
    t     = pk_fnma_hi(u.h[0], Bn, t);
    v2f m = pk_mul_lo(u.h[1], t);
    A     = pk_fma_rot(u.h[1], t, m);
}

// Wave-level DPP lane shifts (single VALU op; proven exact + neutral-cost).
__device__ __forceinline__ float dpp_up1(float v) {   // lane n <- lane n-1
    int i = __builtin_bit_cast(int, v);
    int r = __builtin_amdgcn_update_dpp(i, i, 0x138, 0xF, 0xF, false);  // wave_shr:1
    return __builtin_bit_cast(float, r);
}
__device__ __forceinline__ float dpp_dn1(float v) {   // lane n <- lane n+1
    int i = __builtin_bit_cast(int, v);
    int r = __builtin_amdgcn_update_dpp(i, i, 0x130, 0xF, 0xF, false);  // wave_shl:1
    return __builtin_bit_cast(float, r);
}

// ---------------------------------------------------------------------------
// Kernel 1: transposed coefficient tables (unchanged layout).
//   etab[s][k][lane] (float4 c,sn,sp,cp): even pair p = 8*lane+k, cols 2p,2p+1
//   otab same for odd pair j = 8*lane+k (cols 2j+1,2j+2); j==511 -> identity
//   wtab[q][lane] float4 = (cw0,sw0,cw1,sw1) for cols (16*lane+2q, +2q+1)
// ---------------------------------------------------------------------------
__global__ void coeff_kernel(const float* __restrict__ omega,
                             const float* __restrict__ ETh,
                             const float* __restrict__ OTh,
                             const float* __restrict__ EPh,
                             const float* __restrict__ OPh,
                             float4* __restrict__ etab,
                             float4* __restrict__ otab,
                             float2* __restrict__ wtab)
{
    int idx = blockIdx.x * 256 + threadIdx.x;
    if (idx < NSTEP * 512) {
        int p = idx & 511;
        float c, s, cp, sp;
        __sincosf(ETh[idx], &s, &c);
        __sincosf(EPh[idx], &sp, &cp);
        etab[(idx & ~511) | ((p & 7) << 6) | (p >> 3)] = make_float4(c, s, sp, cp);
    } else if (idx < 2 * NSTEP * 512) {
        int i2 = idx - NSTEP * 512;
        int l = i2 >> 9;
        int j = i2 & 511;
        float4 v;
        if (j < OHH) {
            float c, s, cp, sp;
            __sincosf(OTh[l * OHH + j], &s, &c);
            __sincosf(OPh[l * OHH + j], &sp, &cp);
            v = make_float4(c, s, sp, cp);
        } else {
            v = make_float4(1.f, 0.f, 1.f, 0.f);  // identity rotation
        }
        otab[(i2 & ~511) | ((j & 7) << 6) | (j >> 3)] = v;
    } else if (idx < 2 * NSTEP * 512 + HDIM) {
        int c = idx - 2 * NSTEP * 512;
        float cw, sw;
        __sincosf(omega[c], &sw, &cw);
        int p = c >> 1;
        wtab[(((p & 7) << 6) | (p >> 3)) * 2 + (c & 1)] = make_float2(cw, sw);
    }
}

// ---------------------------------------------------------------------------
// Kernel 2: R=4 rows per wave + packed FP32 math.
//
// Diagnosis (R0/R3 identical walls despite forced pipeline, VGPR 80->152):
// the kernel is coefficient-delivery THROUGHPUT bound: 68 KB/CU/step at a
// measured ~31.5 B/cyc/CU L1 return path = 2176 cyc ~= the 2212 cyc wall;
// VALU (~1000 cyc) hides under it. Only lever: fewer coeff bytes per CU.
// R=4 rows/wave (512 one-wave blocks, 2 waves/CU) halves delivery to
// ~1090 cyc/step; packed VOP3P math keeps VALU (~840 cyc) below that.
// Structure otherwise champion-identical: full H per wave, DPP boundaries,
// no LDS, no barriers, 2-set coefficient prefetch (proven neutral, kept).
// ---------------------------------------------------------------------------
__global__ __launch_bounds__(64, 1) void eunn_kernel(
    const float* __restrict__ x_re,
    const float* __restrict__ x_im,
    const float4* __restrict__ etab,
    const float4* __restrict__ otab,
    const float4* __restrict__ wtab,
    float* __restrict__ out)
{
    const int lane = threadIdx.x;            // block = exactly 1 wave
    const int row0 = blockIdx.x << 2;        // 4 rows per wave
    const int colbase = lane << 4;
    const int lanem1 = (lane + 63) & 63;     // oc0 slot: k=7 of lane-1 (lane0 -> identity)

    v2f x[4][16];   // interleaved (re, im) state: 128 VGPRs

    // current / next step coefficient register sets (17 float4 each)
    float4 cec[8], coc[8], coc0;
    float4 nec[8], noc[8], noc0;

    // --- prologue: issue step-0 coefficient loads first
    {
        const float4* e = etab + lane;
        const float4* o = otab + lane;
        #pragma unroll
        for (int k = 0; k < 8; ++k) cec[k] = e[k << 6];
        #pragma unroll
        for (int k = 0; k < 8; ++k) coc[k] = o[k << 6];
        coc0 = otab[(7 << 6) + lanem1];
    }

    // --- load state (f32 planes), interleave into v2f regs ---
    #pragma unroll
    for (int r = 0; r < 4; ++r) {
        const float4* pr = reinterpret_cast<const float4*>(x_re + (row0 + r) * HDIM + colbase);
        const float4* pi = reinterpret_cast<const float4*>(x_im + (row0 + r) * HDIM + colbase);
        #pragma unroll
        for (int q = 0; q < 4; ++q) {
            float4 vr = pr[q];
            float4 vi = pi[q];
            x[r][4*q+0].x = vr.x; x[r][4*q+0].y = vi.x;
            x[r][4*q+1].x = vr.y; x[r][4*q+1].y = vi.y;
            x[r][4*q+2].x = vr.z; x[r][4*q+2].y = vi.z;
            x[r][4*q+3].x = vr.w; x[r][4*q+3].y = vi.w;
        }
    }

    // one full step's math with coefficient set (ec, oc, oc0)
    auto body = [&](const float4 (&ec)[8], const float4 (&oc)[8], const float4 oc0) {
        // ---- even layer, boundary pairs first (k=0,7)
        #pragma unroll
        for (int r = 0; r < 4; ++r) {
            pair_rotp(ec[0], x[r][0],  x[r][1]);
            pair_rotp(ec[7], x[r][14], x[r][15]);
        }

        // boundary exchange on post-even values via DPP
        v2f xn[4], xl[4];
        #pragma unroll
        for (int r = 0; r < 4; ++r) {
            xn[r].x = dpp_dn1(x[r][0].x);    // right neighbor's col0
            xn[r].y = dpp_dn1(x[r][0].y);
            xl[r].x = dpp_up1(x[r][15].x);   // left neighbor's col15
            xl[r].y = dpp_up1(x[r][15].y);
        }

        // remaining even pairs k=1..6
        #pragma unroll
        for (int k = 1; k < 7; ++k) {
            #pragma unroll
            for (int r = 0; r < 4; ++r)
                pair_rotp(ec[k], x[r][2*k], x[r][2*k+1]);
        }

        // ---- odd layer: internal pairs oc[k-1] -> local cols (2k-1, 2k)
        #pragma unroll
        for (int k = 1; k < 8; ++k) {
            #pragma unroll
            for (int r = 0; r < 4; ++r)
                pair_rotp(oc[k-1], x[r][2*k-1], x[r][2*k]);
        }
        // right boundary (our col15 = "a", neighbor col0 = "b"): update col15
        // (lane63: oc[7] is identity pad, sn=0 -> xn value irrelevant)
        #pragma unroll
        for (int r = 0; r < 4; ++r) pair_rotp_a(oc[7], x[r][15], xn[r]);
        // left boundary (left col15 = "a", our col0 = "b"): update col0
        // (lane0: oc0 is identity, sn=0 -> xl value irrelevant)
        {
            f4p u; u.f = oc0;
            #pragma unroll
            for (int r = 0; r < 4; ++r)
                x[r][0] = pk_fma_hi(u.h[0], xl[r], pk_mul_lo(u.h[0], x[r][0]));
        }
    };

    // 2-step unrolled main loop; coefficient loads issued one full step
    // before first use, pinned by sched_barrier so they cannot sink.
    for (int s = 0; s < NSTEP; s += 2) {
        {   // prefetch step s+1 -> n-set
            const float4* e = etab + (s + 1) * 512 + lane;
            const float4* o = otab + (s + 1) * 512 + lane;
            #pragma unroll
            for (int k = 0; k < 8; ++k) nec[k] = e[k << 6];
            #pragma unroll
            for (int k = 0; k < 8; ++k) noc[k] = o[k << 6];
            noc0 = (otab + (s + 1) * 512)[(7 << 6) + lanem1];
        }
        __builtin_amdgcn_sched_barrier(0);
        body(cec, coc, coc0);

        {   // prefetch step s+2 -> c-set (clamped; last-iter loads unused but valid)
            int s2 = (s + 2 < NSTEP) ? (s + 2) : (NSTEP - 1);
            const float4* e = etab + s2 * 512 + lane;
            const float4* o = otab + s2 * 512 + lane;
            #pragma unroll
            for (int k = 0; k < 8; ++k) cec[k] = e[k << 6];
            #pragma unroll
            for (int k = 0; k < 8; ++k) coc[k] = o[k << 6];
            coc0 = (otab + s2 * 512)[(7 << 6) + lanem1];
        }
        __builtin_amdgcn_sched_barrier(0);
        body(nec, noc, noc0);
    }

    // --- omega phase + de-interleave + store (coalesced) ---
    float4 wc[8];
    #pragma unroll
    for (int q = 0; q < 8; ++q) wc[q] = wtab[(q << 6) + lane];  // (cw0,sw0,cw1,sw1) cols 2q,2q+1

    #pragma unroll
    for (int r = 0; r < 4; ++r) {
        float4* pre = reinterpret_cast<float4*>(out + (row0 + r) * HDIM + colbase);
        float4* pim = reinterpret_cast<float4*>(out + BDIM * HDIM + (row0 + r) * HDIM + colbase);
        #pragma unroll
        for (int h = 0; h < 4; ++h) {
            float4 wa = wc[2*h];      // cols 4h, 4h+1
            float4 wb = wc[2*h + 1];  // cols 4h+2, 4h+3
            v2f X0 = x[r][4*h+0], X1 = x[r][4*h+1], X2 = x[r][4*h+2], X3 = x[r][4*h+3];
            float4 vr, vi;
            vr.x = X0.x * wa.x - X0.y * wa.y;  vi.x = X0.x * wa.y + X0.y * wa.x;
            vr.y = X1.x * wa.z - X1.y * wa.w;  vi.y = X1.x * wa.w + X1.y * wa.z;
            vr.z = X2.x * wb.x - X2.y * wb.y;  vi.z = X2.x * wb.y + X2.y * wb.x;
            vr.w = X3.x * wb.z - X3.y * wb.w;  vi.w = X3.x * wb.w + X3.y * wb.z;
            pre[h] = vr;
            pim[h] = vi;
        }
    }
}

extern "C" void kernel_launch(void* const* d_in, const int* in_sizes, int n_in,
                              void* d_out, int out_size, void* d_ws, size_t ws_size,
                              hipStream_t stream)
{
    const float* x_re  = (const float*)d_in[0];
    const float* x_im  = (const float*)d_in[1];
    const float* omega = (const float*)d_in[2];
    const float* eth   = (const float*)d_in[3];
    const float* oth   = (const float*)d_in[4];
    const float* eph   = (const float*)d_in[5];
    const float* oph   = (const float*)d_in[6];

    char* ws = (char*)d_ws;
    float4* etab = (float4*)ws;                             // 512 KB
    float4* otab = (float4*)(ws + NSTEP * 512 * 16);        // 512 KB
    float2* wtab = (float2*)(ws + 2 * NSTEP * 512 * 16);    // 8 KB

    coeff_kernel<<<260, 256, 0, stream>>>(omega, eth, oth, eph, oph, etab, otab, wtab);
    eunn_kernel<<<BDIM / 4, 64, 0, stream>>>(x_re, x_im, etab, otab,
                                             (const float4*)wtab, (float*)d_out);
}

// Round 5
// 152.109 us; speedup vs baseline: 1.0538x; 1.0538x over previous
//
#include <hip/hip_runtime.h>

#define NSTEP 64
#define HDIM 1024
#define BDIM 2048
#define OHH 511

typedef float v2f __attribute__((ext_vector_type(2)));
typedef float v4f __attribute__((ext_vector_type(4)));

__device__ __forceinline__ v2f vsplat(float s) { v2f r; r.x = s; r.y = s; return r; }

// Non-temporal 16B load: bypass L1 allocation (nt), stream from L2.
// The coefficient table (1 MB) thrashes the 32 KB L1 — measured delivery was
// 31.5 B/cyc/CU ~= half the 64 B/cyc L1 return path, consistent with every
// wave paying the miss/fill path. nt takes L1 out of the loop.
__device__ __forceinline__ v4f ntload(const float4* p) {
    return __builtin_nontemporal_load(reinterpret_cast<const v4f*>(p));
}

// Wave-level DPP lane shifts (single VALU op; proven exact + neutral-cost).
// bound_ctrl=false: edge lane keeps own value; edge uses are either multiplied
// by 0 (identity rotations) or explicitly overridden (oc0 lane0 cndmask).
__device__ __forceinline__ float dpp_up1(float v) {   // lane n <- lane n-1
    int i = __builtin_bit_cast(int, v);
    int r = __builtin_amdgcn_update_dpp(i, i, 0x138, 0xF, 0xF, false);  // wave_shr:1
    return __builtin_bit_cast(float, r);
}
__device__ __forceinline__ float dpp_dn1(float v) {   // lane n <- lane n+1
    int i = __builtin_bit_cast(int, v);
    int r = __builtin_amdgcn_update_dpp(i, i, 0x130, 0xF, 0xF, false);  // wave_shl:1
    return __builtin_bit_cast(float, r);
}

// ---------------------------------------------------------------------------
// Kernel 1: coefficient table, transposed slot layout (unchanged math) but
// even+odd MERGED into one contiguous 16 KB slice per step:
//   ctab[s*1024 + slot]        even pair p, slot = ((p&7)<<6)|(p>>3)
//   ctab[s*1024 + 512 + slot]  odd  pair j, same slot formula; j==511 -> identity
//   wtab[q][lane] float4 = (cw0,sw0,cw1,sw1) for cols (16*lane+2q, +2q+1)
// Contiguity removes the 512-KB-apart set aliasing between the two streams.
// ---------------------------------------------------------------------------
__global__ void coeff_kernel(const float* __restrict__ omega,
                             const float* __restrict__ ETh,
                             const float* __restrict__ OTh,
                             const float* __restrict__ EPh,
                             const float* __restrict__ OPh,
                             float4* __restrict__ ctab,
                             float2* __restrict__ wtab)
{
    int idx = blockIdx.x * 256 + threadIdx.x;
    if (idx < NSTEP * 512) {
        int s = idx >> 9;
        int p = idx & 511;
        float c, sn, cp, sp;
        __sincosf(ETh[idx], &sn, &c);
        __sincosf(EPh[idx], &sp, &cp);
        ctab[(s << 10) | ((p & 7) << 6) | (p >> 3)] = make_float4(c, sn, sp, cp);
    } else if (idx < 2 * NSTEP * 512) {
        int i2 = idx - NSTEP * 512;
        int s = i2 >> 9;
        int j = i2 & 511;
        float4 v;
        if (j < OHH) {
            float c, sn, cp, sp;
            __sincosf(OTh[s * OHH + j], &sn, &c);
            __sincosf(OPh[s * OHH + j], &sp, &cp);
            v = make_float4(c, sn, sp, cp);
        } else {
            v = make_float4(1.f, 0.f, 1.f, 0.f);  // identity rotation
        }
        ctab[(s << 10) | 512 | ((j & 7) << 6) | (j >> 3)] = v;
    } else if (idx < 2 * NSTEP * 512 + HDIM) {
        int c = idx - 2 * NSTEP * 512;
        float cw, sw;
        __sincosf(omega[c], &sw, &cw);
        int p = c >> 1;
        wtab[(((p & 7) << 6) | (p >> 3)) * 2 + (c & 1)] = make_float2(cw, sw);
    }
}

// Packed complex pair rotation: state A,B are (re,im) v2f; f = (c,sn,sp,cp).
//   t = c*A - sn*B;  B' = c*B + sn*A;  A' = (sp + i*cp) * t
__device__ __forceinline__ void pair_rot(const v4f f, v2f& A, v2f& B) {
    v2f C = vsplat(f.x), S = vsplat(f.y);
    v2f t = C * A - S * B;
    B = C * B + S * A;
    v2f cps; cps.x = -f.w; cps.y = f.w;
    A = vsplat(f.z) * t + cps * t.yx;
}
// Right-boundary variant: update A only, Bn is neighbor's value.
__device__ __forceinline__ void pair_rot_a(const v4f f, v2f& A, const v2f Bn) {
    v2f t = vsplat(f.x) * A - vsplat(f.y) * Bn;
    v2f cps; cps.x = -f.w; cps.y = f.w;
    A = vsplat(f.z) * t + cps * t.yx;
}

// ---------------------------------------------------------------------------
// Kernel 2: champion body (wave = 2 rows, full H, DPP boundaries, no LDS, no
// barrier, explicit 2-set one-step-ahead prefetch — R3-proven schedule) with
// the coefficient stream moved OFF the L1 fill path:
//   - all coefficient loads are non-temporal (L2-direct)
//   - per-step slice contiguous 16 KB (merged ctab)
//   - oc0 (17th load) replaced by 2 DPPs on oc[7] + lane0 identity cndmask
// Diagnosis recap: R0 vs R3 proved delivery-THROUGHPUT bound at 31.5 B/cyc/CU
// ~= half the L1 return path; hypothesis = L1 thrash puts every wave on the
// fill path. Expected: delivery ~68 KB @ >=56 B/cyc ~= 1100-1200 cyc/step,
// wall -> max(delivery, VALU ~1000) ~= 33-38 us.
// ---------------------------------------------------------------------------
__global__ __launch_bounds__(256, 1) void eunn_kernel(
    const float* __restrict__ x_re,
    const float* __restrict__ x_im,
    const float4* __restrict__ ctab,
    const float4* __restrict__ wtab,
    float* __restrict__ out)
{
    const int lane = threadIdx.x & 63;
    const int wave = threadIdx.x >> 6;
    const int row0 = blockIdx.x * 8 + wave * 2;
    const int colbase = lane << 4;

    v2f x[2][16];   // interleaved (re, im) state

    // current / next step coefficient register sets (16 float4 each)
    v4f cec[8], coc[8];
    v4f nec[8], noc[8];

    // --- prologue: issue step-0 coefficient loads first
    {
        const float4* b = ctab + lane;
        #pragma unroll
        for (int k = 0; k < 8; ++k) cec[k] = ntload(b + (k << 6));
        #pragma unroll
        for (int k = 0; k < 8; ++k) coc[k] = ntload(b + 512 + (k << 6));
    }

    // --- load state (f32 planes), interleave into v2f regs ---
    #pragma unroll
    for (int r = 0; r < 2; ++r) {
        const float4* pr = reinterpret_cast<const float4*>(x_re + (row0 + r) * HDIM + colbase);
        const float4* pi = reinterpret_cast<const float4*>(x_im + (row0 + r) * HDIM + colbase);
        #pragma unroll
        for (int q = 0; q < 4; ++q) {
            float4 vr = pr[q];
            float4 vi = pi[q];
            x[r][4*q+0].x = vr.x; x[r][4*q+0].y = vi.x;
            x[r][4*q+1].x = vr.y; x[r][4*q+1].y = vi.y;
            x[r][4*q+2].x = vr.z; x[r][4*q+2].y = vi.z;
            x[r][4*q+3].x = vr.w; x[r][4*q+3].y = vi.w;
        }
    }

    // one full step's math with coefficient set (ec, oc)
    auto body = [&](const v4f (&ec)[8], const v4f (&oc)[8]) {
        // ---- even layer, boundary pairs first (k=0,7)
        pair_rot(ec[0], x[0][0],  x[0][1]);
        pair_rot(ec[0], x[1][0],  x[1][1]);
        pair_rot(ec[7], x[0][14], x[0][15]);
        pair_rot(ec[7], x[1][14], x[1][15]);

        // boundary exchange on post-even values via DPP (VALU, ~2 cyc each)
        v2f xn[2], xl[2];
        #pragma unroll
        for (int r = 0; r < 2; ++r) {
            xn[r].x = dpp_dn1(x[r][0].x);    // right neighbor's col0
            xn[r].y = dpp_dn1(x[r][0].y);
            xl[r].x = dpp_up1(x[r][15].x);   // left neighbor's col15
            xl[r].y = dpp_up1(x[r][15].y);
        }

        // oc0 (left-boundary coeffs = lane-1's oc[7]) via DPP instead of a
        // 17th load; lane0 needs the j=-1 identity -> force (C,S)=(1,0).
        float c0 = dpp_up1(oc[7].x);
        float s0 = dpp_up1(oc[7].y);
        if (lane == 0) { c0 = 1.0f; s0 = 0.0f; }

        // remaining even pairs k=1..6
        #pragma unroll
        for (int k = 1; k < 7; ++k) {
            pair_rot(ec[k], x[0][2*k], x[0][2*k+1]);
            pair_rot(ec[k], x[1][2*k], x[1][2*k+1]);
        }

        // ---- odd layer: internal pairs oc[k-1] -> local cols (2k-1, 2k)
        #pragma unroll
        for (int k = 1; k < 8; ++k) {
            pair_rot(oc[k-1], x[0][2*k-1], x[0][2*k]);
            pair_rot(oc[k-1], x[1][2*k-1], x[1][2*k]);
        }
        // right boundary (our col15 = "a", neighbor col0 = "b"): update col15
        // (lane63: oc[7] is identity pad, sn=0 -> xn value irrelevant)
        pair_rot_a(oc[7], x[0][15], xn[0]);
        pair_rot_a(oc[7], x[1][15], xn[1]);
        // left boundary (left col15 = "a", our col0 = "b"): update col0
        // (lane0: forced identity above -> xl value irrelevant)
        {
            v2f C = vsplat(c0), S = vsplat(s0);
            x[0][0] = C * x[0][0] + S * xl[0];
            x[1][0] = C * x[1][0] + S * xl[1];
        }
    };

    // 2-step unrolled main loop; coefficient loads issued one full step
    // before first use, pinned by sched_barrier so they cannot sink.
    for (int s = 0; s < NSTEP; s += 2) {
        {   // prefetch step s+1 -> n-set
            const float4* b = ctab + ((s + 1) << 10) + lane;
            #pragma unroll
            for (int k = 0; k < 8; ++k) nec[k] = ntload(b + (k << 6));
            #pragma unroll
            for (int k = 0; k < 8; ++k) noc[k] = ntload(b + 512 + (k << 6));
        }
        __builtin_amdgcn_sched_barrier(0);
        body(cec, coc);

        {   // prefetch step s+2 -> c-set (clamped; last-iter loads unused but valid)
            int s2 = (s + 2 < NSTEP) ? (s + 2) : (NSTEP - 1);
            const float4* b = ctab + (s2 << 10) + lane;
            #pragma unroll
            for (int k = 0; k < 8; ++k) cec[k] = ntload(b + (k << 6));
            #pragma unroll
            for (int k = 0; k < 8; ++k) coc[k] = ntload(b + 512 + (k << 6));
        }
        __builtin_amdgcn_sched_barrier(0);
        body(nec, noc);
    }

    // --- omega phase + de-interleave + store (coalesced) ---
    float4 wc[8];
    #pragma unroll
    for (int q = 0; q < 8; ++q) wc[q] = wtab[(q << 6) + lane];  // (cw0,sw0,cw1,sw1) cols 2q,2q+1

    #pragma unroll
    for (int r = 0; r < 2; ++r) {
        float4* pre = reinterpret_cast<float4*>(out + (row0 + r) * HDIM + colbase);
        float4* pim = reinterpret_cast<float4*>(out + BDIM * HDIM + (row0 + r) * HDIM + colbase);
        #pragma unroll
        for (int h = 0; h < 4; ++h) {
            float4 wa = wc[2*h];      // cols 4h, 4h+1
            float4 wb = wc[2*h + 1];  // cols 4h+2, 4h+3
            v2f X0 = x[r][4*h+0], X1 = x[r][4*h+1], X2 = x[r][4*h+2], X3 = x[r][4*h+3];
            float4 vr, vi;
            vr.x = X0.x * wa.x - X0.y * wa.y;  vi.x = X0.x * wa.y + X0.y * wa.x;
            vr.y = X1.x * wa.z - X1.y * wa.w;  vi.y = X1.x * wa.w + X1.y * wa.z;
            vr.z = X2.x * wb.x - X2.y * wb.y;  vi.z = X2.x * wb.y + X2.y * wb.x;
            vr.w = X3.x * wb.z - X3.y * wb.w;  vi.w = X3.x * wb.w + X3.y * wb.z;
            pre[h] = vr;
            pim[h] = vi;
        }
    }
}

extern "C" void kernel_launch(void* const* d_in, const int* in_sizes, int n_in,
                              void* d_out, int out_size, void* d_ws, size_t ws_size,
                              hipStream_t stream)
{
    const float* x_re  = (const float*)d_in[0];
    const float* x_im  = (const float*)d_in[1];
    const float* omega = (const float*)d_in[2];
    const float* eth   = (const float*)d_in[3];
    const float* oth   = (const float*)d_in[4];
    const float* eph   = (const float*)d_in[5];
    const float* oph   = (const float*)d_in[6];

    char* ws = (char*)d_ws;
    float4* ctab = (float4*)ws;                             // 64*1024*16 = 1 MB
    float2* wtab = (float2*)(ws + NSTEP * 1024 * 16);       // 8 KB

    coeff_kernel<<<260, 256, 0, stream>>>(omega, eth, oth, eph, oph, ctab, wtab);
    eunn_kernel<<<BDIM / 8, 256, 0, stream>>>(x_re, x_im, ctab,
                                              (const float4*)wtab, (float*)d_out);
}

// Round 6
// 130.012 us; speedup vs baseline: 1.2329x; 1.1700x over previous
//
#include <hip/hip_runtime.h>

#define NSTEP 64
#define HDIM 1024
#define BDIM 2048
#define OHH 511

typedef float v2f __attribute__((ext_vector_type(2)));
typedef float v4f __attribute__((ext_vector_type(4)));

__device__ __forceinline__ v2f vsplat(float s) { v2f r; r.x = s; r.y = s; return r; }

// Wave-level DPP lane shifts (single VALU op; proven exact + neutral-cost).
__device__ __forceinline__ float dpp_up1(float v) {   // lane n <- lane n-1
    int i = __builtin_bit_cast(int, v);
    int r = __builtin_amdgcn_update_dpp(i, i, 0x138, 0xF, 0xF, false);  // wave_shr:1
    return __builtin_bit_cast(float, r);
}
__device__ __forceinline__ float dpp_dn1(float v) {   // lane n <- lane n+1
    int i = __builtin_bit_cast(int, v);
    int r = __builtin_amdgcn_update_dpp(i, i, 0x130, 0xF, 0xF, false);  // wave_shl:1
    return __builtin_bit_cast(float, r);
}

// Async global->LDS DMA, 16 B per lane: LDS dest = wave-uniform base + lane*16,
// global src per-lane. (Compiled & correctness-proven in R2.)
__device__ __forceinline__ void stage16(const float4* g, const float4* l) {
    __builtin_amdgcn_global_load_lds(
        (const __attribute__((address_space(1))) void*)g,
        (__attribute__((address_space(3))) void*)l,
        16, 0, 0);
}

// ---------------------------------------------------------------------------
// Kernel 1: merged coefficient table (R5 layout, kept — contiguous 16 KB
// per-step slices are exactly what the group-staging DMA wants):
//   ctab[s*1024 + slot]        even pair p, slot = ((p&7)<<6)|(p>>3)
//   ctab[s*1024 + 512 + slot]  odd  pair j, same slot formula; j==511 -> identity
//   wtab[q][lane] float4 = (cw0,sw0,cw1,sw1) for cols (16*lane+2q, +2q+1)
// ---------------------------------------------------------------------------
__global__ void coeff_kernel(const float* __restrict__ omega,
                             const float* __restrict__ ETh,
                             const float* __restrict__ OTh,
                             const float* __restrict__ EPh,
                             const float* __restrict__ OPh,
                             float4* __restrict__ ctab,
                             float2* __restrict__ wtab)
{
    int idx = blockIdx.x * 256 + threadIdx.x;
    if (idx < NSTEP * 512) {
        int s = idx >> 9;
        int p = idx & 511;
        float c, sn, cp, sp;
        __sincosf(ETh[idx], &sn, &c);
        __sincosf(EPh[idx], &sp, &cp);
        ctab[(s << 10) | ((p & 7) << 6) | (p >> 3)] = make_float4(c, sn, sp, cp);
    } else if (idx < 2 * NSTEP * 512) {
        int i2 = idx - NSTEP * 512;
        int s = i2 >> 9;
        int j = i2 & 511;
        float4 v;
        if (j < OHH) {
            float c, sn, cp, sp;
            __sincosf(OTh[s * OHH + j], &sn, &c);
            __sincosf(OPh[s * OHH + j], &sp, &cp);
            v = make_float4(c, sn, sp, cp);
        } else {
            v = make_float4(1.f, 0.f, 1.f, 0.f);  // identity rotation
        }
        ctab[(s << 10) | 512 | ((j & 7) << 6) | (j >> 3)] = v;
    } else if (idx < 2 * NSTEP * 512 + HDIM) {
        int c = idx - 2 * NSTEP * 512;
        float cw, sw;
        __sincosf(omega[c], &sw, &cw);
        int p = c >> 1;
        wtab[(((p & 7) << 6) | (p >> 3)) * 2 + (c & 1)] = make_float2(cw, sw);
    }
}

// Packed complex pair rotation: state A,B are (re,im) v2f; f = (c,sn,sp,cp).
//   t = c*A - sn*B;  B' = c*B + sn*A;  A' = (sp + i*cp) * t
__device__ __forceinline__ void pair_rot(const v4f f, v2f& A, v2f& B) {
    v2f C = vsplat(f.x), S = vsplat(f.y);
    v2f t = C * A - S * B;
    B = C * B + S * A;
    v2f cps; cps.x = -f.w; cps.y = f.w;
    A = vsplat(f.z) * t + cps * t.yx;
}
// Right-boundary variant: update A only, Bn is neighbor's value.
__device__ __forceinline__ void pair_rot_a(const v4f f, v2f& A, const v2f Bn) {
    v2f t = vsplat(f.x) * A - vsplat(f.y) * Bn;
    v2f cps; cps.x = -f.w; cps.y = f.w;
    A = vsplat(f.z) * t + cps * t.yx;
}

// ---------------------------------------------------------------------------
// Kernel 2: champion math body (R=2 rows/wave, full H, DPP boundaries,
// oc0-via-DPP) + 4-STEP-GROUP LDS coefficient staging, double-buffered.
//
// Model (fits R0/R3/R5): champion saturates the per-CU vector-memory return
// path at ~32 B/cyc — 68 KB/CU/step = 2176 cyc ~= the 2212 cyc wall; VALU
// (~1000 cyc) hides under it. R3 (prefetch) neutral: can't pipeline a
// saturated pipe. R5 (L1 bypass) worse: L2 path slower still. Fix = move
// delivery to the LDS pipe. R2 failed doing this with per-step barriers +
// unpipelined ds_reads; here: stage 4 steps (64 KB) per barrier (17 barriers
// vs 64, each with ~4400 cyc slack vs 2048-cyc staging), ds_reads
// double-set prefetched one step ahead (R3 schedule). Per step per CU:
// vector pipe 16 KB (544 cyc, was 2176), LDS ~64 KB (~770 cyc), VALU ~840.
// ---------------------------------------------------------------------------
__global__ __launch_bounds__(256, 1) void eunn_kernel(
    const float* __restrict__ x_re,
    const float* __restrict__ x_im,
    const float4* __restrict__ ctab,
    const float4* __restrict__ wtab,
    float* __restrict__ out)
{
    const int lane = threadIdx.x & 63;
    const int wave = threadIdx.x >> 6;
    const int row0 = blockIdx.x * 8 + wave * 2;
    const int colbase = lane << 4;

    // [buf][step-in-group][slot]  = 2 x 4 x 16 KB = 128 KB
    __shared__ float4 cbuf[2][4][1024];

    v2f x[2][16];   // interleaved (re, im) state

    // --- stage group 0 (steps 0..3): wave w DMAs step w's 16 KB slice
    {
        const float4* src = ctab + (wave << 10) + lane;
        float4* dst = &cbuf[0][wave][0];
        #pragma unroll
        for (int c = 0; c < 16; ++c) stage16(src + (c << 6), dst + (c << 6));
    }

    // --- load state (f32 planes), interleave into v2f regs ---
    #pragma unroll
    for (int r = 0; r < 2; ++r) {
        const float4* pr = reinterpret_cast<const float4*>(x_re + (row0 + r) * HDIM + colbase);
        const float4* pi = reinterpret_cast<const float4*>(x_im + (row0 + r) * HDIM + colbase);
        #pragma unroll
        for (int q = 0; q < 4; ++q) {
            float4 vr = pr[q];
            float4 vi = pi[q];
            x[r][4*q+0].x = vr.x; x[r][4*q+0].y = vi.x;
            x[r][4*q+1].x = vr.y; x[r][4*q+1].y = vi.y;
            x[r][4*q+2].x = vr.z; x[r][4*q+2].y = vi.z;
            x[r][4*q+3].x = vr.w; x[r][4*q+3].y = vi.w;
        }
    }

    __syncthreads();   // group-0 slices resident (vmcnt(0)+lgkmcnt(0)+barrier)

    v4f cec[8], coc[8], nec[8], noc[8];

    // read one step's coefficient slice from LDS (16x ds_read_b128,
    // lane-stride 16 B = m134's 85 B/cyc conflict-free pattern)
    auto ldcoef = [&](int buf, int t, v4f (&ec)[8], v4f (&oc)[8]) {
        const float4* b = &cbuf[buf][t][lane];
        #pragma unroll
        for (int k = 0; k < 8; ++k) ec[k] = *reinterpret_cast<const v4f*>(b + (k << 6));
        #pragma unroll
        for (int k = 0; k < 8; ++k) oc[k] = *reinterpret_cast<const v4f*>(b + 512 + (k << 6));
    };

    // one full step's math (R5 body, correctness-proven incl. oc0-via-DPP)
    auto body = [&](const v4f (&ec)[8], const v4f (&oc)[8]) {
        // ---- even layer, boundary pairs first (k=0,7)
        pair_rot(ec[0], x[0][0],  x[0][1]);
        pair_rot(ec[0], x[1][0],  x[1][1]);
        pair_rot(ec[7], x[0][14], x[0][15]);
        pair_rot(ec[7], x[1][14], x[1][15]);

        // boundary exchange on post-even values via DPP
        v2f xn[2], xl[2];
        #pragma unroll
        for (int r = 0; r < 2; ++r) {
            xn[r].x = dpp_dn1(x[r][0].x);    // right neighbor's col0
            xn[r].y = dpp_dn1(x[r][0].y);
            xl[r].x = dpp_up1(x[r][15].x);   // left neighbor's col15
            xl[r].y = dpp_up1(x[r][15].y);
        }

        // oc0 (left-boundary coeffs = lane-1's oc[7]) via DPP; lane0 -> identity
        float c0 = dpp_up1(oc[7].x);
        float s0 = dpp_up1(oc[7].y);
        if (lane == 0) { c0 = 1.0f; s0 = 0.0f; }

        // remaining even pairs k=1..6
        #pragma unroll
        for (int k = 1; k < 7; ++k) {
            pair_rot(ec[k], x[0][2*k], x[0][2*k+1]);
            pair_rot(ec[k], x[1][2*k], x[1][2*k+1]);
        }

        // ---- odd layer: internal pairs oc[k-1] -> local cols (2k-1, 2k)
        #pragma unroll
        for (int k = 1; k < 8; ++k) {
            pair_rot(oc[k-1], x[0][2*k-1], x[0][2*k]);
            pair_rot(oc[k-1], x[1][2*k-1], x[1][2*k]);
        }
        // right boundary: update col15 (lane63: oc[7] identity pad, sn=0)
        pair_rot_a(oc[7], x[0][15], xn[0]);
        pair_rot_a(oc[7], x[1][15], xn[1]);
        // left boundary: update col0 (lane0: forced identity above)
        {
            v2f C = vsplat(c0), S = vsplat(s0);
            x[0][0] = C * x[0][0] + S * xl[0];
            x[1][0] = C * x[1][0] + S * xl[1];
        }
    };

    ldcoef(0, 0, cec, coc);   // group-0 step-0 coeffs (latency eaten once/group)

    int buf = 0;
    for (int g = 0; g < 16; ++g) {
        // issue next group's staging DMA first: 4400 cyc of compute to land
        if (g < 15) {
            const float4* src = ctab + ((((g + 1) << 2) + wave) << 10) + lane;
            float4* dst = &cbuf[buf ^ 1][wave][0];
            #pragma unroll
            for (int c = 0; c < 16; ++c) stage16(src + (c << 6), dst + (c << 6));
        }
        // 4 steps, coefficient ds_reads one step ahead (cur/nxt sets)
        ldcoef(buf, 1, nec, noc);
        __builtin_amdgcn_sched_barrier(0);
        body(cec, coc);
        ldcoef(buf, 2, cec, coc);
        __builtin_amdgcn_sched_barrier(0);
        body(nec, noc);
        ldcoef(buf, 3, nec, noc);
        __builtin_amdgcn_sched_barrier(0);
        body(cec, coc);
        body(nec, noc);
        // one barrier per group: publishes next buffer (vmcnt0) and
        // republishes this buffer for overwrite. No state crosses it.
        __syncthreads();
        buf ^= 1;
        if (g < 15) ldcoef(buf, 0, cec, coc);   // next group's step-0
    }

    // --- omega phase + de-interleave + store (coalesced) ---
    float4 wc[8];
    #pragma unroll
    for (int q = 0; q < 8; ++q) wc[q] = wtab[(q << 6) + lane];  // (cw0,sw0,cw1,sw1) cols 2q,2q+1

    #pragma unroll
    for (int r = 0; r < 2; ++r) {
        float4* pre = reinterpret_cast<float4*>(out + (row0 + r) * HDIM + colbase);
        float4* pim = reinterpret_cast<float4*>(out + BDIM * HDIM + (row0 + r) * HDIM + colbase);
        #pragma unroll
        for (int h = 0; h < 4; ++h) {
            float4 wa = wc[2*h];      // cols 4h, 4h+1
            float4 wb = wc[2*h + 1];  // cols 4h+2, 4h+3
            v2f X0 = x[r][4*h+0], X1 = x[r][4*h+1], X2 = x[r][4*h+2], X3 = x[r][4*h+3];
            float4 vr, vi;
            vr.x = X0.x * wa.x - X0.y * wa.y;  vi.x = X0.x * wa.y + X0.y * wa.x;
            vr.y = X1.x * wa.z - X1.y * wa.w;  vi.y = X1.x * wa.w + X1.y * wa.z;
            vr.z = X2.x * wb.x - X2.y * wb.y;  vi.z = X2.x * wb.y + X2.y * wb.x;
            vr.w = X3.x * wb.z - X3.y * wb.w;  vi.w = X3.x * wb.w + X3.y * wb.z;
            pre[h] = vr;
            pim[h] = vi;
        }
    }
}

extern "C" void kernel_launch(void* const* d_in, const int* in_sizes, int n_in,
                              void* d_out, int out_size, void* d_ws, size_t ws_size,
                              hipStream_t stream)
{
    const float* x_re  = (const float*)d_in[0];
    const float* x_im  = (const float*)d_in[1];
    const float* omega = (const float*)d_in[2];
    const float* eth   = (const float*)d_in[3];
    const float* oth   = (const float*)d_in[4];
    const float* eph   = (const float*)d_in[5];
    const float* oph   = (const float*)d_in[6];

    char* ws = (char*)d_ws;
    float4* ctab = (float4*)ws;                             // 64*1024*16 = 1 MB
    float2* wtab = (float2*)(ws + NSTEP * 1024 * 16);       // 8 KB

    coeff_kernel<<<260, 256, 0, stream>>>(omega, eth, oth, eph, oph, ctab, wtab);
    eunn_kernel<<<BDIM / 8, 256, 0, stream>>>(x_re, x_im, ctab,
                                              (const float4*)wtab, (float*)d_out);
}